// Round 8
// baseline (1053.858 us; speedup 1.0000x reference)
//
#include <hip/hip_runtime.h>
#include <math.h>

// ---------------------------------------------------------------------------
// GatedNNMF: h=gelu(x@U_w^T+U_b); z1,z2=split(h); xm=relu(LN(z2));
// NMF2D(xm, bases, 6 steps) -> z2r; out=(z1*z2r)@V_w^T+V_b
// B=8 S=1024 F=1024 FFN=4096 Nc=2048 R=64
// All NMF matmuls on MFMA (bf16 hi/lo split emulation of fp32).
// Round 8: coef_step/bases_step/gram64p K-loops are now BARRIER-FREE:
// MFMA fragments load directly from global (same values the LDS staging
// produced; L2-resident operands), letting the compiler deep-pipeline
// loads. NKS 8->16. MFMA accumulation order unchanged (bit-identical).
// gemm_bt/ln/transpose/conv/recon byte-identical to r7.
// ---------------------------------------------------------------------------

typedef __bf16 bf16;
typedef bf16 bf16x4 __attribute__((ext_vector_type(4)));
typedef bf16 bf16x8 __attribute__((ext_vector_type(8)));
typedef float f32x4 __attribute__((ext_vector_type(4)));

#define NMF_EPS 1e-6f
#define LNEPS   1e-5f
#define NKS     16     // gram K-split factor

#if defined(__has_builtin)
#if __has_builtin(__builtin_amdgcn_global_load_lds)
#define HAS_GLL 1
#endif
#endif

__device__ __forceinline__ void split2(float x, bf16& h, bf16& l) {
    h = (bf16)x;
    l = (bf16)(x - (float)h);
}

// ---------------- dtype probe: fp32 data viewed as bf16 -> huge/NaN ---------
__global__ __launch_bounds__(256) void detect_dtype(const void* x, int* flag) {
    __shared__ int bad_sh;
    if (threadIdx.x == 0) bad_sh = 0;
    __syncthreads();
    const bf16* p = (const bf16*)x;
    int bad = 0;
    for (int i = threadIdx.x; i < 1024; i += 256) {
        float f = (float)p[i];
        if (!(fabsf(f) < 1000.f)) bad = 1;   // catches NaN too
    }
    if (bad) atomicOr(&bad_sh, 1);
    __syncthreads();
    if (threadIdx.x == 0) *flag = bad_sh;    // 1 => inputs are fp32
}

// ---- fused input normalization: all 8 tensors -> bf16 arena, one launch ----
__global__ __launch_bounds__(256)
void conv_all(const void* s0, const void* s1, const void* s2, const void* s3,
              const void* s4, const void* s5, const void* s6, const void* s7,
              bf16* __restrict__ ar, const int* __restrict__ flag) {
    const int is_f32 = *flag;
    const int total4 = 3688704;
    for (int i = blockIdx.x * 256 + threadIdx.x; i < total4; i += gridDim.x * 256) {
        const void* src; int loc; size_t doff;
        if (i < 2097152)      { src = s0; loc = i;           doff = 0; }
        else if (i < 3145728) { src = s1; loc = i - 2097152; doff = 8388608; }
        else if (i < 3146752) { src = s2; loc = i - 3145728; doff = 12582912; }
        else if (i < 3147264) { src = s3; loc = i - 3146752; doff = 12587008; }
        else if (i < 3147776) { src = s4; loc = i - 3147264; doff = 12589056; }
        else if (i < 3164160) { src = s5; loc = i - 3147776; doff = 12591104; }
        else if (i < 3688448) { src = s6; loc = i - 3164160; doff = 12656640; }
        else                  { src = s7; loc = i - 3688448; doff = 14753792; }
        bf16x4 o;
        if (is_f32) {
            f32x4 v = ((const f32x4*)src)[loc];
            o[0] = (bf16)v[0]; o[1] = (bf16)v[1]; o[2] = (bf16)v[2]; o[3] = (bf16)v[3];
        } else {
            o = ((const bf16x4*)src)[loc];
        }
        *(bf16x4*)(ar + doff + (size_t)loc * 4) = o;
    }
}

// ---------------- MFMA GEMM: C = A(M,K) @ B(N,K)^T, bf16 in, fp32 acc -------
// EPI 0: v=gelu(v+bias); n<2048 -> o0 (bf16 z1), else o1 (bf16 z2), both (M,2048)
// EPI 1: v+=bias; store to outf (fp32) if *flag else outb (bf16), (M,N)
// Staging: global_load_lds (wave-uniform LDS base; HW adds lane*16B).
template <int EPI>
__global__ __launch_bounds__(256)
void gemm_bt(const bf16* __restrict__ A, const bf16* __restrict__ B,
             const bf16* __restrict__ bias,
             bf16* __restrict__ o0, bf16* __restrict__ o1,
             float* __restrict__ outf, bf16* __restrict__ outb,
             int K, int N, const int* __restrict__ flag) {
    __shared__ bf16 As[128 * 32];
    __shared__ bf16 Bs[128 * 32];
    const int tid = threadIdx.x;
    const int bm = blockIdx.x, bn = blockIdx.y;
    const bf16* Ab = A + (size_t)bm * 128 * K;
    const bf16* Bb = B + (size_t)bn * 128 * K;
    const int w = tid >> 6, lane = tid & 63, lm = lane & 15, lq = lane >> 4;
    const int m_off = (w >> 1) * 64, n_off = (w & 1) * 64;
    const int of32 = (EPI == 1) ? *flag : 0;
    f32x4 acc[4][4];
#pragma unroll
    for (int i = 0; i < 4; i++)
#pragma unroll
        for (int j = 0; j < 4; j++) { acc[i][j][0]=0.f; acc[i][j][1]=0.f; acc[i][j][2]=0.f; acc[i][j][3]=0.f; }

    const int r0 = tid * 8;            // per-lane element offset (16B per lane)
    const int row0 = r0 >> 5, col0 = r0 & 31;
    const int wb = w * 512;            // wave-uniform element base (w*1024B)
    for (int k0 = 0; k0 < K; k0 += 32) {
        __syncthreads();
        const bf16* gA0 = Ab + (size_t)row0 * K        + k0 + col0;
        const bf16* gA1 = Ab + (size_t)(row0 + 64) * K + k0 + col0;
        const bf16* gB0 = Bb + (size_t)row0 * K        + k0 + col0;
        const bf16* gB1 = Bb + (size_t)(row0 + 64) * K + k0 + col0;
#ifdef HAS_GLL
        __builtin_amdgcn_global_load_lds((const __attribute__((address_space(1))) void*)gA0,
                                         (__attribute__((address_space(3))) void*)&As[wb], 16, 0, 0);
        __builtin_amdgcn_global_load_lds((const __attribute__((address_space(1))) void*)gA1,
                                         (__attribute__((address_space(3))) void*)&As[wb + 2048], 16, 0, 0);
        __builtin_amdgcn_global_load_lds((const __attribute__((address_space(1))) void*)gB0,
                                         (__attribute__((address_space(3))) void*)&Bs[wb], 16, 0, 0);
        __builtin_amdgcn_global_load_lds((const __attribute__((address_space(1))) void*)gB1,
                                         (__attribute__((address_space(3))) void*)&Bs[wb + 2048], 16, 0, 0);
#else
        *(int4*)(&As[r0])        = *(const int4*)gA0;
        *(int4*)(&As[r0 + 2048]) = *(const int4*)gA1;
        *(int4*)(&Bs[r0])        = *(const int4*)gB0;
        *(int4*)(&Bs[r0 + 2048]) = *(const int4*)gB1;
#endif
        __syncthreads();
        bf16x8 af[4], bg[4];
#pragma unroll
        for (int i = 0; i < 4; i++) af[i] = *(const bf16x8*)&As[(m_off + i * 16 + lm) * 32 + lq * 8];
#pragma unroll
        for (int j = 0; j < 4; j++) bg[j] = *(const bf16x8*)&Bs[(n_off + j * 16 + lm) * 32 + lq * 8];
#pragma unroll
        for (int i = 0; i < 4; i++)
#pragma unroll
            for (int j = 0; j < 4; j++)
                acc[i][j] = __builtin_amdgcn_mfma_f32_16x16x32_bf16(af[i], bg[j], acc[i][j], 0, 0, 0);
    }
    const int gm0 = bm * 128 + m_off, gn0 = bn * 128 + n_off;
#pragma unroll
    for (int i = 0; i < 4; i++) {
#pragma unroll
        for (int j = 0; j < 4; j++) {
            const int gn = gn0 + j * 16 + lm;
            const float bv = (float)bias[gn];
#pragma unroll
            for (int e = 0; e < 4; e++) {
                const int gm = gm0 + i * 16 + lq * 4 + e;
                float v = acc[i][j][e] + bv;
                if (EPI == 0) {
                    v = 0.5f * v * (1.f + erff(v * 0.70710678118654752f));
                    if (gn < 2048) o0[(size_t)gm * 2048 + gn] = (bf16)v;
                    else           o1[(size_t)gm * 2048 + (gn - 2048)] = (bf16)v;
                } else {
                    if (of32) outf[(size_t)gm * N + gn] = v;
                    else      outb[(size_t)gm * N + gn] = (bf16)v;
                }
            }
        }
    }
}

// ---------------- LayerNorm(2048) + ReLU, in-place bf16 ---------------------
__global__ __launch_bounds__(256)
void ln_relu(bf16* __restrict__ z, const bf16* __restrict__ g, const bf16* __restrict__ b) {
    const int row = blockIdx.x;
    bf16* zr = z + (size_t)row * 2048;
    const int t = threadIdx.x;
    bf16x4 a0 = *(bf16x4*)(zr + t * 4);
    bf16x4 a1 = *(bf16x4*)(zr + 1024 + t * 4);
    float v0[4], v1[4];
#pragma unroll
    for (int i = 0; i < 4; i++) { v0[i] = (float)a0[i]; v1[i] = (float)a1[i]; }
    float s = 0.f, q = 0.f;
#pragma unroll
    for (int i = 0; i < 4; i++) { s += v0[i] + v1[i]; q += v0[i] * v0[i] + v1[i] * v1[i]; }
#pragma unroll
    for (int off = 32; off >= 1; off >>= 1) { s += __shfl_down(s, off); q += __shfl_down(q, off); }
    __shared__ float red[8];
    __shared__ float mv[2];
    const int wv = t >> 6;
    if ((t & 63) == 0) { red[wv] = s; red[4 + wv] = q; }
    __syncthreads();
    if (t == 0) {
        float S = red[0] + red[1] + red[2] + red[3];
        float Q = red[4] + red[5] + red[6] + red[7];
        float mu = S * (1.f / 2048.f);
        float var = Q * (1.f / 2048.f) - mu * mu;
        mv[0] = mu; mv[1] = rsqrtf(var + LNEPS);
    }
    __syncthreads();
    const float mu = mv[0], ri = mv[1];
#pragma unroll
    for (int i = 0; i < 4; i++) {
        int c0 = t * 4 + i, c1 = 1024 + t * 4 + i;
        a0[i] = (bf16)fmaxf((v0[i] - mu) * ri * (float)g[c0] + (float)b[c0], 0.f);
        a1[i] = (bf16)fmaxf((v1[i] - mu) * ri * (float)g[c1] + (float)b[c1], 0.f);
    }
    *(bf16x4*)(zr + t * 4) = a0;
    *(bf16x4*)(zr + 1024 + t * 4) = a1;
}

// ---------------- xmB [b][d=1024][n=2048] -> xmT [b][n][d] ------------------
__global__ __launch_bounds__(256)
void transpose_xm(const bf16* __restrict__ src, bf16* __restrict__ dst) {
    // grid: (32 ntile, 16 dtile, 8 b)
    const int n0 = blockIdx.x * 64, d0 = blockIdx.y * 64, b = blockIdx.z;
    const bf16* S = src + (size_t)b * 1024 * 2048;
    bf16* Dst = dst + (size_t)b * 2048 * 1024;
    __shared__ bf16 tl[64 * 72];
    const int t = threadIdx.x;
    const int tr = t >> 2, tc = (t & 3) * 16;
    bf16x8 v0 = *(const bf16x8*)(S + (size_t)(d0 + tr) * 2048 + n0 + tc);
    bf16x8 v1 = *(const bf16x8*)(S + (size_t)(d0 + tr) * 2048 + n0 + tc + 8);
    *(bf16x8*)&tl[tr * 72 + tc] = v0;
    *(bf16x8*)&tl[tr * 72 + tc + 8] = v1;
    __syncthreads();
    bf16 o[16];
#pragma unroll
    for (int i = 0; i < 16; i++) o[i] = tl[(tc + i) * 72 + tr];
    *(bf16x8*)(Dst + (size_t)(n0 + tr) * 1024 + d0 + tc) = *(bf16x8*)&o[0];
    *(bf16x8*)(Dst + (size_t)(n0 + tr) * 1024 + d0 + tc + 8) = *(bf16x8*)&o[8];
}

// ---- bases init: b0 bf16 [1024][64] -> fp32 state + bf16 hi/lo mirrors -----
__global__ __launch_bounds__(256)
void bases_init2(const bf16* __restrict__ b0, float* __restrict__ bases,
                 bf16* __restrict__ bNh, bf16* __restrict__ bNl,
                 bf16* __restrict__ bTh, bf16* __restrict__ bTl) {
    // grid (16 dtile, 8 b)
    const int d0 = blockIdx.x * 64, b = blockIdx.y;
    __shared__ bf16 tl[64 * 72];
    const int t = threadIdx.x;
    const int tr = t >> 2, tc = (t & 3) * 16;
    bf16x8 v0 = *(const bf16x8*)(b0 + (size_t)(d0 + tr) * 64 + tc);
    bf16x8 v1 = *(const bf16x8*)(b0 + (size_t)(d0 + tr) * 64 + tc + 8);
    *(bf16x8*)&tl[tr * 72 + tc] = v0;
    *(bf16x8*)&tl[tr * 72 + tc + 8] = v1;
    bf16x8 zz;
#pragma unroll
    for (int i = 0; i < 8; i++) zz[i] = (bf16)0.f;
    f32x4 f0, f1, f2, f3;
#pragma unroll
    for (int i = 0; i < 4; i++) { f0[i]=(float)v0[i]; f1[i]=(float)v0[i+4]; f2[i]=(float)v1[i]; f3[i]=(float)v1[i+4]; }
    const size_t nb = (size_t)b * 1024 * 64 + (size_t)(d0 + tr) * 64 + tc;
    *(f32x4*)(bases + nb)      = f0;
    *(f32x4*)(bases + nb + 4)  = f1;
    *(f32x4*)(bases + nb + 8)  = f2;
    *(f32x4*)(bases + nb + 12) = f3;
    *(bf16x8*)(bNh + nb)     = v0;
    *(bf16x8*)(bNh + nb + 8) = v1;
    *(bf16x8*)(bNl + nb)     = zz;
    *(bf16x8*)(bNl + nb + 8) = zz;
    __syncthreads();
    bf16 o[16];
#pragma unroll
    for (int i = 0; i < 16; i++) o[i] = tl[(tc + i) * 72 + tr];
    const size_t tb = (size_t)b * 64 * 1024 + (size_t)tr * 1024 + d0 + tc;
    *(bf16x8*)(bTh + tb)     = *(bf16x8*)&o[0];
    *(bf16x8*)(bTh + tb + 8) = *(bf16x8*)&o[8];
    *(bf16x8*)(bTl + tb)     = zz;
    *(bf16x8*)(bTl + tb + 8) = zz;
}

// ---- gram64p: partial gram over a K-slice. grid (NKS ksplit, 8 b) ----------
// Gp[b][ks][r][s] = sum_{k in slice} T[r][k]T[s][k]; 3-term hi/lo MFMA.
// Barrier-free: fragments load directly from global (T is L2-resident).
__global__ __launch_bounds__(256)
void gram64p(const bf16* __restrict__ Th, const bf16* __restrict__ Tl,
             int K, float* __restrict__ Gp) {
    const int ks = blockIdx.x, b = blockIdx.y;
    const int KC = K / NKS;
    const int kbeg = ks * KC, kend = kbeg + KC;
    const bf16* H = Th + (size_t)b * 64 * K;
    const bf16* L = Tl + (size_t)b * 64 * K;
    const int t = threadIdx.x, lane = t & 63, w = t >> 6;
    const int lm = lane & 15, lq = lane >> 4;
    const bf16* Ha = H + (size_t)(w * 16 + lm) * K + lq * 8;   // a-frag base
    const bf16* La = L + (size_t)(w * 16 + lm) * K + lq * 8;
    const bf16* Hb = H + (size_t)lm * K + lq * 8;              // + j*16*K
    const bf16* Lb = L + (size_t)lm * K + lq * 8;
    f32x4 acc[4];
#pragma unroll
    for (int j = 0; j < 4; j++) { acc[j][0]=0.f; acc[j][1]=0.f; acc[j][2]=0.f; acc[j][3]=0.f; }
    for (int k0 = kbeg; k0 < kend; k0 += 32) {
        bf16x8 aH = *(const bf16x8*)(Ha + k0);
        bf16x8 aL = *(const bf16x8*)(La + k0);
#pragma unroll
        for (int j = 0; j < 4; j++) {
            bf16x8 bH = *(const bf16x8*)(Hb + (size_t)j * 16 * K + k0);
            bf16x8 bL = *(const bf16x8*)(Lb + (size_t)j * 16 * K + k0);
            acc[j] = __builtin_amdgcn_mfma_f32_16x16x32_bf16(aH, bH, acc[j], 0, 0, 0);
            acc[j] = __builtin_amdgcn_mfma_f32_16x16x32_bf16(aH, bL, acc[j], 0, 0, 0);
            acc[j] = __builtin_amdgcn_mfma_f32_16x16x32_bf16(aL, bH, acc[j], 0, 0, 0);
        }
    }
    float* Gb = Gp + ((size_t)b * NKS + ks) * 4096;
#pragma unroll
    for (int j = 0; j < 4; j++)
#pragma unroll
        for (int e = 0; e < 4; e++)
            Gb[(w * 16 + lq * 4 + e) * 64 + j * 16 + lm] = acc[j][e];
}

// ---- coef step: num = xm^T @ bases via MFMA (A=xmT, W=basesT hi/lo) --------
// Barrier-free K-loop: fragments load directly from global.
// MODE 0: coef = softmax_r(num); MODE 1: coef *= num/(coef@btb+eps),
// btb = sum of NKS partials; writes fp32 + hi/lo mirrors.
// grid (32 ntiles of 64, 8 b); 256 thr; per-wave: 16 n rows x 64 r
template <int MODE>
__global__ __launch_bounds__(256)
void coef_step(const bf16* __restrict__ xmT, const bf16* __restrict__ bTh,
               const bf16* __restrict__ bTl, const float* __restrict__ btb,
               float* __restrict__ coef,
               bf16* __restrict__ cNh, bf16* __restrict__ cNl,
               bf16* __restrict__ cTh, bf16* __restrict__ cTl) {
    const int n0 = blockIdx.x * 64, b = blockIdx.y;
    const bf16* X = xmT + (size_t)b * 2048 * 1024 + (size_t)n0 * 1024;
    const bf16* H = bTh + (size_t)b * 64 * 1024;
    const bf16* L = bTl + (size_t)b * 64 * 1024;
    __shared__ float cold[(MODE == 1) ? 64 * 65 : 1];
    __shared__ float gsm[(MODE == 1) ? 64 * 64 : 1];
    const int t = threadIdx.x;
    float* Cb = coef + (size_t)b * 2048 * 64 + (size_t)n0 * 64;
    if constexpr (MODE == 1) {
        const int rr = t >> 2, cc = (t & 3) * 16;
#pragma unroll
        for (int i = 0; i < 4; i++)
            *(f32x4*)&cold[rr * 65 + cc + i * 4] = *(const f32x4*)(Cb + (size_t)rr * 64 + cc + i * 4);
        const float* Gb = btb + (size_t)b * NKS * 4096;
#pragma unroll
        for (int i = 0; i < 4; i++) {
            f32x4 s4; s4[0]=0.f; s4[1]=0.f; s4[2]=0.f; s4[3]=0.f;
#pragma unroll
            for (int ks = 0; ks < NKS; ks++)
                s4 += *(const f32x4*)(Gb + ks * 4096 + rr * 64 + cc + i * 4);
            *(f32x4*)&gsm[rr * 64 + cc + i * 4] = s4;
        }
    }
    const int lane = t & 63, w = t >> 6, lm = lane & 15, lq = lane >> 4;
    const bf16* Xr = X + (size_t)(w * 16 + lm) * 1024 + lq * 8;  // a-frag base
    const bf16* Hr = H + (size_t)lm * 1024 + lq * 8;             // + j*16*1024
    const bf16* Lr = L + (size_t)lm * 1024 + lq * 8;
    f32x4 acc[4];
#pragma unroll
    for (int j = 0; j < 4; j++) { acc[j][0]=0.f; acc[j][1]=0.f; acc[j][2]=0.f; acc[j][3]=0.f; }
#pragma unroll 2
    for (int k0 = 0; k0 < 1024; k0 += 64) {
        bf16x8 a0 = *(const bf16x8*)(Xr + k0);
        bf16x8 a1 = *(const bf16x8*)(Xr + k0 + 32);
#pragma unroll
        for (int j = 0; j < 4; j++) {
            bf16x8 bh0 = *(const bf16x8*)(Hr + (size_t)j * 16 * 1024 + k0);
            bf16x8 bl0 = *(const bf16x8*)(Lr + (size_t)j * 16 * 1024 + k0);
            acc[j] = __builtin_amdgcn_mfma_f32_16x16x32_bf16(a0, bh0, acc[j], 0, 0, 0);
            acc[j] = __builtin_amdgcn_mfma_f32_16x16x32_bf16(a0, bl0, acc[j], 0, 0, 0);
            bf16x8 bh1 = *(const bf16x8*)(Hr + (size_t)j * 16 * 1024 + k0 + 32);
            bf16x8 bl1 = *(const bf16x8*)(Lr + (size_t)j * 16 * 1024 + k0 + 32);
            acc[j] = __builtin_amdgcn_mfma_f32_16x16x32_bf16(a1, bh1, acc[j], 0, 0, 0);
            acc[j] = __builtin_amdgcn_mfma_f32_16x16x32_bf16(a1, bl1, acc[j], 0, 0, 0);
        }
    }
    if constexpr (MODE == 1) __syncthreads();   // cold/gsm preload visible
    // num value acc[j][e] lives at n-local = w*16+lq*4+e, r = j*16+lm
    const int nbase = w * 16 + lq * 4;
    float out[4][4];
    if constexpr (MODE == 0) {
#pragma unroll
        for (int e = 0; e < 4; e++) {
            float m = fmaxf(fmaxf(acc[0][e], acc[1][e]), fmaxf(acc[2][e], acc[3][e]));
#pragma unroll
            for (int off = 1; off < 16; off <<= 1) m = fmaxf(m, __shfl_xor(m, off));
            float ex[4], s = 0.f;
#pragma unroll
            for (int j = 0; j < 4; j++) { ex[j] = expf(acc[j][e] - m); s += ex[j]; }
#pragma unroll
            for (int off = 1; off < 16; off <<= 1) s += __shfl_xor(s, off);
            const float inv = 1.f / s;
#pragma unroll
            for (int j = 0; j < 4; j++) out[j][e] = ex[j] * inv;
        }
    } else {
        float den[4][4];
#pragma unroll
        for (int j = 0; j < 4; j++)
#pragma unroll
            for (int e = 0; e < 4; e++) den[j][e] = 0.f;
#pragma unroll 8
        for (int s = 0; s < 64; s++) {
            float g4[4], c4[4];
#pragma unroll
            for (int j = 0; j < 4; j++) g4[j] = gsm[s * 64 + j * 16 + lm];
#pragma unroll
            for (int e = 0; e < 4; e++) c4[e] = cold[(nbase + e) * 65 + s];
#pragma unroll
            for (int j = 0; j < 4; j++)
#pragma unroll
                for (int e = 0; e < 4; e++) den[j][e] += c4[e] * g4[j];
        }
#pragma unroll
        for (int j = 0; j < 4; j++)
#pragma unroll
            for (int e = 0; e < 4; e++)
                out[j][e] = cold[(nbase + e) * 65 + j * 16 + lm] * acc[j][e] / (den[j][e] + NMF_EPS);
    }
    // fp32 canonical (+ N mirrors in MODE 1)
#pragma unroll
    for (int j = 0; j < 4; j++) {
        const int r = j * 16 + lm;
#pragma unroll
        for (int e = 0; e < 4; e++) {
            const int nl = nbase + e;
            Cb[(size_t)nl * 64 + r] = out[j][e];
            if constexpr (MODE == 1) {
                bf16 h, l2;
                split2(out[j][e], h, l2);
                cNh[(size_t)b * 2048 * 64 + (size_t)(n0 + nl) * 64 + r] = h;
                cNl[(size_t)b * 2048 * 64 + (size_t)(n0 + nl) * 64 + r] = l2;
            }
        }
    }
    if constexpr (MODE == 1) {
        // T mirrors via LDS transpose (reuse cold as [r][65] tile)
        __syncthreads();
#pragma unroll
        for (int j = 0; j < 4; j++)
#pragma unroll
            for (int e = 0; e < 4; e++)
                cold[(j * 16 + lm) * 65 + nbase + e] = out[j][e];
        __syncthreads();
        const int rr = t >> 2, nc = (t & 3) * 16;
        bf16 hh[16], ll2[16];
#pragma unroll
        for (int i = 0; i < 16; i++) split2(cold[rr * 65 + nc + i], hh[i], ll2[i]);
        const size_t tb = (size_t)b * 64 * 2048 + (size_t)rr * 2048 + n0 + nc;
        *(bf16x8*)(cTh + tb)     = *(bf16x8*)&hh[0];
        *(bf16x8*)(cTh + tb + 8) = *(bf16x8*)&hh[8];
        *(bf16x8*)(cTl + tb)     = *(bf16x8*)&ll2[0];
        *(bf16x8*)(cTl + tb + 8) = *(bf16x8*)&ll2[8];
    }
}

// ---- bases step: numT = coefT @ xm^T via MFMA (A=coefT hi/lo, W=xm) --------
// Barrier-free K-loop: fragments load directly from global.
// ctc = sum of NKS partials. bases[d][r] *= num/(bases@ctc + eps);
// grid (32 dtiles of 32, 8 b)
__global__ __launch_bounds__(256)
void bases_step(const bf16* __restrict__ xm, const bf16* __restrict__ cTh,
                const bf16* __restrict__ cTl, const float* __restrict__ ctc,
                float* __restrict__ bases,
                bf16* __restrict__ bNh, bf16* __restrict__ bNl,
                bf16* __restrict__ bTh, bf16* __restrict__ bTl) {
    const int d0 = blockIdx.x * 32, b = blockIdx.y;
    const bf16* X = xm + (size_t)b * 1024 * 2048 + (size_t)d0 * 2048;
    const bf16* H = cTh + (size_t)b * 64 * 2048;
    const bf16* L = cTl + (size_t)b * 64 * 2048;
    __shared__ float bold[32 * 65];
    __shared__ float gsm[64 * 64];
    const int t = threadIdx.x;
    float* Bb = bases + (size_t)b * 1024 * 64 + (size_t)d0 * 64;
    {
        const int rr = t >> 3, cc = (t & 7) * 8;
        *(f32x4*)&bold[rr * 65 + cc]     = *(const f32x4*)(Bb + (size_t)rr * 64 + cc);
        *(f32x4*)&bold[rr * 65 + cc + 4] = *(const f32x4*)(Bb + (size_t)rr * 64 + cc + 4);
        const int r2 = t >> 2, c2 = (t & 3) * 16;
        const float* Gb = ctc + (size_t)b * NKS * 4096;
#pragma unroll
        for (int i = 0; i < 4; i++) {
            f32x4 s4; s4[0]=0.f; s4[1]=0.f; s4[2]=0.f; s4[3]=0.f;
#pragma unroll
            for (int ks = 0; ks < NKS; ks++)
                s4 += *(const f32x4*)(Gb + ks * 4096 + r2 * 64 + c2 + i * 4);
            *(f32x4*)&gsm[r2 * 64 + c2 + i * 4] = s4;
        }
    }
    const int lane = t & 63, w = t >> 6, lm = lane & 15, lq = lane >> 4;
    const bf16* Hr = H + (size_t)(w * 16 + lm) * 2048 + lq * 8;  // a-frag base
    const bf16* Lr = L + (size_t)(w * 16 + lm) * 2048 + lq * 8;
    const bf16* Xr = X + (size_t)lm * 2048 + lq * 8;             // + j*16*2048
    f32x4 acc[2];
#pragma unroll
    for (int j = 0; j < 2; j++) { acc[j][0]=0.f; acc[j][1]=0.f; acc[j][2]=0.f; acc[j][3]=0.f; }
#pragma unroll 2
    for (int k0 = 0; k0 < 2048; k0 += 64) {
        bf16x8 ah0 = *(const bf16x8*)(Hr + k0);
        bf16x8 al0 = *(const bf16x8*)(Lr + k0);
        bf16x8 ah1 = *(const bf16x8*)(Hr + k0 + 32);
        bf16x8 al1 = *(const bf16x8*)(Lr + k0 + 32);
#pragma unroll
        for (int j = 0; j < 2; j++) {
            bf16x8 bx0 = *(const bf16x8*)(Xr + (size_t)j * 16 * 2048 + k0);
            acc[j] = __builtin_amdgcn_mfma_f32_16x16x32_bf16(ah0, bx0, acc[j], 0, 0, 0);
            acc[j] = __builtin_amdgcn_mfma_f32_16x16x32_bf16(al0, bx0, acc[j], 0, 0, 0);
            bf16x8 bx1 = *(const bf16x8*)(Xr + (size_t)j * 16 * 2048 + k0 + 32);
            acc[j] = __builtin_amdgcn_mfma_f32_16x16x32_bf16(ah1, bx1, acc[j], 0, 0, 0);
            acc[j] = __builtin_amdgcn_mfma_f32_16x16x32_bf16(al1, bx1, acc[j], 0, 0, 0);
        }
    }
    __syncthreads();   // bold/gsm preload visible
    // numT value acc[j][e] at r = w*16+lq*4+e, d-local = j*16+lm
    const int rbase = w * 16 + lq * 4;
    float den[2][4];
#pragma unroll
    for (int j = 0; j < 2; j++)
#pragma unroll
        for (int e = 0; e < 4; e++) den[j][e] = 0.f;
#pragma unroll 8
    for (int s = 0; s < 64; s++) {
        float g4[4], b2[2];
#pragma unroll
        for (int e = 0; e < 4; e++) g4[e] = gsm[s * 64 + rbase + e];
#pragma unroll
        for (int j = 0; j < 2; j++) b2[j] = bold[(j * 16 + lm) * 65 + s];
#pragma unroll
        for (int j = 0; j < 2; j++)
#pragma unroll
            for (int e = 0; e < 4; e++) den[j][e] += b2[j] * g4[e];
    }
    float out[2][4];
#pragma unroll
    for (int j = 0; j < 2; j++)
#pragma unroll
        for (int e = 0; e < 4; e++)
            out[j][e] = bold[(j * 16 + lm) * 65 + rbase + e] * acc[j][e] / (den[j][e] + NMF_EPS);
    __syncthreads();
#pragma unroll
    for (int j = 0; j < 2; j++)
#pragma unroll
        for (int e = 0; e < 4; e++)
            bold[(j * 16 + lm) * 65 + rbase + e] = out[j][e];
    __syncthreads();
    {   // fp32 + N mirrors
        const int dd = t >> 3, rc = (t & 7) * 8;
        float v[8];
#pragma unroll
        for (int i = 0; i < 8; i++) v[i] = bold[dd * 65 + rc + i];
        *(f32x4*)(Bb + (size_t)dd * 64 + rc)     = *(f32x4*)&v[0];
        *(f32x4*)(Bb + (size_t)dd * 64 + rc + 4) = *(f32x4*)&v[4];
        bf16 hv[8], lv[8];
#pragma unroll
        for (int i = 0; i < 8; i++) split2(v[i], hv[i], lv[i]);
        const size_t nb = (size_t)b * 1024 * 64 + (size_t)(d0 + dd) * 64 + rc;
        *(bf16x8*)(bNh + nb) = *(bf16x8*)&hv[0];
        *(bf16x8*)(bNl + nb) = *(bf16x8*)&lv[0];
    }
    {   // T mirrors
        const int rr = t >> 2, dc = (t & 3) * 8;
        bf16 hv[8], lv[8];
#pragma unroll
        for (int i = 0; i < 8; i++) split2(bold[(dc + i) * 65 + rr], hv[i], lv[i]);
        const size_t tb = (size_t)b * 64 * 1024 + (size_t)rr * 1024 + d0 + dc;
        *(bf16x8*)(bTh + tb) = *(bf16x8*)&hv[0];
        *(bf16x8*)(bTl + tb) = *(bf16x8*)&lv[0];
    }
}

// ---- recon+gate: z1A[s][n] *= sum_r bases[s][r]*coef[n][r] via MFMA (K=64) -
// grid (16 ntiles of 128, 8 stiles of 128, 8 b)
__global__ __launch_bounds__(256)
void recon_gate2(bf16* __restrict__ z1A, const bf16* __restrict__ bNh,
                 const bf16* __restrict__ bNl, const bf16* __restrict__ cNh,
                 const bf16* __restrict__ cNl) {
    const int n0 = blockIdx.x * 128, s0 = blockIdx.y * 128, b = blockIdx.z;
    const bf16* Ah = bNh + (size_t)b * 1024 * 64 + (size_t)s0 * 64;
    const bf16* Al = bNl + (size_t)b * 1024 * 64 + (size_t)s0 * 64;
    const bf16* Bh = cNh + (size_t)b * 2048 * 64 + (size_t)n0 * 64;
    const bf16* Bl = cNl + (size_t)b * 2048 * 64 + (size_t)n0 * 64;
    __shared__ bf16 ahs[128 * 72], als[128 * 72], bhs[128 * 72], bls[128 * 72];
    const int t = threadIdx.x;
#pragma unroll
    for (int i = 0; i < 4; i++) {
        const int idx = t * 4 + i;            // 0..1023 chunks of 8
        const int r_ = idx >> 3, c_ = (idx & 7) * 8;
        *(int4*)&ahs[r_ * 72 + c_] = *(const int4*)(Ah + (size_t)r_ * 64 + c_);
        *(int4*)&als[r_ * 72 + c_] = *(const int4*)(Al + (size_t)r_ * 64 + c_);
        *(int4*)&bhs[r_ * 72 + c_] = *(const int4*)(Bh + (size_t)r_ * 64 + c_);
        *(int4*)&bls[r_ * 72 + c_] = *(const int4*)(Bl + (size_t)r_ * 64 + c_);
    }
    __syncthreads();
    const int lane = t & 63, w = t >> 6, lm = lane & 15, lq = lane >> 4;
    const int m_off = (w >> 1) * 64, n_off = (w & 1) * 64;
    f32x4 acc[4][4];
#pragma unroll
    for (int i = 0; i < 4; i++)
#pragma unroll
        for (int j = 0; j < 4; j++) { acc[i][j][0]=0.f; acc[i][j][1]=0.f; acc[i][j][2]=0.f; acc[i][j][3]=0.f; }
#pragma unroll
    for (int kk = 0; kk < 2; kk++) {
        bf16x8 afh[4], afl[4], bgh[4], bgl[4];
#pragma unroll
        for (int i = 0; i < 4; i++) {
            afh[i] = *(const bf16x8*)&ahs[(m_off + i * 16 + lm) * 72 + kk * 32 + lq * 8];
            afl[i] = *(const bf16x8*)&als[(m_off + i * 16 + lm) * 72 + kk * 32 + lq * 8];
        }
#pragma unroll
        for (int j = 0; j < 4; j++) {
            bgh[j] = *(const bf16x8*)&bhs[(n_off + j * 16 + lm) * 72 + kk * 32 + lq * 8];
            bgl[j] = *(const bf16x8*)&bls[(n_off + j * 16 + lm) * 72 + kk * 32 + lq * 8];
        }
#pragma unroll
        for (int i = 0; i < 4; i++)
#pragma unroll
            for (int j = 0; j < 4; j++) {
                acc[i][j] = __builtin_amdgcn_mfma_f32_16x16x32_bf16(afh[i], bgh[j], acc[i][j], 0, 0, 0);
                acc[i][j] = __builtin_amdgcn_mfma_f32_16x16x32_bf16(afh[i], bgl[j], acc[i][j], 0, 0, 0);
                acc[i][j] = __builtin_amdgcn_mfma_f32_16x16x32_bf16(afl[i], bgh[j], acc[i][j], 0, 0, 0);
            }
    }
    bf16* Z = z1A + ((size_t)b * 1024 + s0) * 2048 + n0;
#pragma unroll
    for (int i = 0; i < 4; i++)
#pragma unroll
        for (int j = 0; j < 4; j++) {
            const int gn = n_off + j * 16 + lm;
#pragma unroll
            for (int e = 0; e < 4; e++) {
                const int gm = m_off + i * 16 + lq * 4 + e;
                bf16* p = Z + (size_t)gm * 2048 + gn;
                *p = (bf16)((float)*p * acc[i][j][e]);
            }
        }
}

// ---------------------------------------------------------------------------
extern "C" void kernel_launch(void* const* d_in, const int* in_sizes, int n_in,
                              void* d_out, int out_size, void* d_ws, size_t ws_size,
                              hipStream_t stream) {
    (void)in_sizes; (void)n_in; (void)out_size; (void)ws_size;
    char* ws = (char*)d_ws;
    bf16*  z1A   = (bf16*)(ws);                   // 33554432 B (z1 -> gated A)
    bf16*  xmB   = (bf16*)(ws + 33554432);        // 33554432 B (z2 -> xm, [b][d][n])
    bf16*  xmT   = (bf16*)(ws + 67108864);        // 33554432 B (xm^T, [b][n][d])
    char*  ar    = ws + 100663296;                // bf16 input arena (~29.5 MB)
    bf16* xc   = (bf16*)(ar);                     // 8388608 el
    bf16* Uwc  = (bf16*)(ar + 16777216);          // 4194304
    bf16* Ubc  = (bf16*)(ar + 25165824);          // 4096
    bf16* lngc = (bf16*)(ar + 25174016);          // 2048
    bf16* lnbc = (bf16*)(ar + 25178112);          // 2048
    bf16* b0c  = (bf16*)(ar + 25182208);          // 65536
    bf16* Vwc  = (bf16*)(ar + 25313280);          // 2097152
    bf16* Vbc  = (bf16*)(ar + 29507584);          // 1024
    int*  dflag = (int*)(ar + 29509632);
    // NMF state overlays the arena prefix (xc/Uwc), which is dead after gemm0:
    float* bases = (float*)(ar);                  // 2097152
    float* coef  = (float*)(ar + 2097152);        // 4194304
    bf16* bTh = (bf16*)(ar + 6291456);            // 1048576 each
    bf16* bTl = (bf16*)(ar + 7340032);
    bf16* bNh = (bf16*)(ar + 8388608);
    bf16* bNl = (bf16*)(ar + 9437184);
    bf16* cTh = (bf16*)(ar + 10485760);           // 2097152 each
    bf16* cTl = (bf16*)(ar + 12582912);
    bf16* cNh = (bf16*)(ar + 14680064);
    bf16* cNl = (bf16*)(ar + 16777216);           // ends ar+18874368
    // Partial grams live in dead Uwc tail (free after gemm0):
    float* btb = (float*)(ar + 18874368);         // NKS=16 partials: 2097152 B
    float* ctc = (float*)(ar + 20971520);         // NKS=16 partials: 2097152 B
    // ends ar+23068672 < Ubc @ ar+25165824. Peak ws usage ~130.2 MB (= r4).

    detect_dtype<<<1, 256, 0, stream>>>(d_in[0], dflag);
    conv_all<<<dim3(2048), 256, 0, stream>>>(d_in[0], d_in[1], d_in[2], d_in[3],
                                             d_in[4], d_in[5], d_in[6], d_in[7],
                                             (bf16*)ar, dflag);

    // 1) h = gelu(x @ U_w^T + U_b) -> z1 (bf16) | z2 (bf16, xmB)
    gemm_bt<0><<<dim3(64, 32), 256, 0, stream>>>(xc, Uwc, Ubc, z1A, xmB,
                                                 nullptr, nullptr, 1024, 4096, nullptr);
    // 2) xm = relu(LN(z2)) in place; then materialize xm^T
    ln_relu<<<dim3(8192), 256, 0, stream>>>(xmB, lngc, lnbc);
    transpose_xm<<<dim3(32, 16, 8), 256, 0, stream>>>(xmB, xmT);
    // 3) NMF (fp32 state + bf16 hi/lo mirrors; all matmuls on MFMA)
    bases_init2<<<dim3(16, 8), 256, 0, stream>>>(b0c, bases, bNh, bNl, bTh, bTl);
    coef_step<0><<<dim3(32, 8), 256, 0, stream>>>(xmT, bTh, bTl, nullptr, coef,
                                                  nullptr, nullptr, nullptr, nullptr);
    for (int it = 0; it < 7; ++it) {
        gram64p<<<dim3(NKS, 8), 256, 0, stream>>>(bTh, bTl, 1024, btb);
        coef_step<1><<<dim3(32, 8), 256, 0, stream>>>(xmT, bTh, bTl, btb, coef,
                                                      cNh, cNl, cTh, cTl);
        if (it < 6) {
            gram64p<<<dim3(NKS, 8), 256, 0, stream>>>(cTh, cTl, 2048, ctc);
            bases_step<<<dim3(32, 8), 256, 0, stream>>>(xmB, cTh, cTl, ctc, bases,
                                                        bNh, bNl, bTh, bTl);
        }
    }
    // 4) A = z1 * (bases @ coef^T), in place over z1A (MFMA, K=64, 3-term)
    recon_gate2<<<dim3(16, 8, 8), 256, 0, stream>>>(z1A, bNh, bNl, cNh, cNl);
    // 5) out = A @ V_w^T + V_b   (fp32 out if inputs were fp32, else bf16)
    gemm_bt<1><<<dim3(64, 8), 256, 0, stream>>>(z1A, Vwc, Vbc, nullptr, nullptr,
                                                (float*)d_out, (bf16*)d_out,
                                                2048, 1024, dflag);
}

// Round 9
// 753.609 us; speedup vs baseline: 1.3984x; 1.3984x over previous
//
#include <hip/hip_runtime.h>
#include <math.h>

// ---------------------------------------------------------------------------
// GatedNNMF: h=gelu(x@U_w^T+U_b); z1,z2=split(h); xm=relu(LN(z2));
// NMF2D(xm, bases, 6 steps) -> z2r; out=(z1*z2r)@V_w^T+V_b
// B=8 S=1024 F=1024 FFN=4096 Nc=2048 R=64
// All NMF matmuls on MFMA (bf16 hi/lo split emulation of fp32).
// Round 9: FULL REVERT of r8's barrier-free experiment (regressed 775->1054;
// uncoalesced direct-global fragments lose to staged LDS). Step/gram kernels
// = r7 verbatim (NKS=8, LDS-staged, dbuf steps). ONE new variable:
// gemm_bt<0> epilogue's erff -> branch-free A&S-7.1.26 erf (~12 VALU ops,
// |err|<1.5e-7) — r7 counters showed VALUBusy 63% / MfmaUtil 22%, i.e. the
// GELU epilogue rivals the K-loop.
// ---------------------------------------------------------------------------

typedef __bf16 bf16;
typedef bf16 bf16x4 __attribute__((ext_vector_type(4)));
typedef bf16 bf16x8 __attribute__((ext_vector_type(8)));
typedef float f32x4 __attribute__((ext_vector_type(4)));

#define NMF_EPS 1e-6f
#define LNEPS   1e-5f
#define NKS     8      // gram K-split factor

#if defined(__has_builtin)
#if __has_builtin(__builtin_amdgcn_global_load_lds)
#define HAS_GLL 1
#endif
#endif

__device__ __forceinline__ void split2(float x, bf16& h, bf16& l) {
    h = (bf16)x;
    l = (bf16)(x - (float)h);
}

// exact-GELU via branch-free erf (Abramowitz-Stegun 7.1.26, |err|<1.5e-7)
__device__ __forceinline__ float gelu_fast(float v) {
    const float x = v * 0.70710678118654752f;
    const float ax = fabsf(x);
    const float t = __builtin_amdgcn_rcpf(fmaf(0.3275911f, ax, 1.f));
    float p = fmaf(t, 1.061405429f, -1.453152027f);
    p = fmaf(t, p, 1.421413741f);
    p = fmaf(t, p, -0.284496736f);
    p = fmaf(t, p, 0.254829592f);
    p = p * t;
    const float er = copysignf(fmaf(-p, __expf(-ax * ax), 1.f), x);
    return 0.5f * v * (1.f + er);
}

// ---------------- dtype probe: fp32 data viewed as bf16 -> huge/NaN ---------
__global__ __launch_bounds__(256) void detect_dtype(const void* x, int* flag) {
    __shared__ int bad_sh;
    if (threadIdx.x == 0) bad_sh = 0;
    __syncthreads();
    const bf16* p = (const bf16*)x;
    int bad = 0;
    for (int i = threadIdx.x; i < 1024; i += 256) {
        float f = (float)p[i];
        if (!(fabsf(f) < 1000.f)) bad = 1;   // catches NaN too
    }
    if (bad) atomicOr(&bad_sh, 1);
    __syncthreads();
    if (threadIdx.x == 0) *flag = bad_sh;    // 1 => inputs are fp32
}

// ---- fused input normalization: all 8 tensors -> bf16 arena, one launch ----
__global__ __launch_bounds__(256)
void conv_all(const void* s0, const void* s1, const void* s2, const void* s3,
              const void* s4, const void* s5, const void* s6, const void* s7,
              bf16* __restrict__ ar, const int* __restrict__ flag) {
    const int is_f32 = *flag;
    const int total4 = 3688704;
    for (int i = blockIdx.x * 256 + threadIdx.x; i < total4; i += gridDim.x * 256) {
        const void* src; int loc; size_t doff;
        if (i < 2097152)      { src = s0; loc = i;           doff = 0; }
        else if (i < 3145728) { src = s1; loc = i - 2097152; doff = 8388608; }
        else if (i < 3146752) { src = s2; loc = i - 3145728; doff = 12582912; }
        else if (i < 3147264) { src = s3; loc = i - 3146752; doff = 12587008; }
        else if (i < 3147776) { src = s4; loc = i - 3147264; doff = 12589056; }
        else if (i < 3164160) { src = s5; loc = i - 3147776; doff = 12591104; }
        else if (i < 3688448) { src = s6; loc = i - 3164160; doff = 12656640; }
        else                  { src = s7; loc = i - 3688448; doff = 14753792; }
        bf16x4 o;
        if (is_f32) {
            f32x4 v = ((const f32x4*)src)[loc];
            o[0] = (bf16)v[0]; o[1] = (bf16)v[1]; o[2] = (bf16)v[2]; o[3] = (bf16)v[3];
        } else {
            o = ((const bf16x4*)src)[loc];
        }
        *(bf16x4*)(ar + doff + (size_t)loc * 4) = o;
    }
}

// ---------------- MFMA GEMM: C = A(M,K) @ B(N,K)^T, bf16 in, fp32 acc -------
// EPI 0: v=gelu(v+bias); n<2048 -> o0 (bf16 z1), else o1 (bf16 z2), both (M,2048)
// EPI 1: v+=bias; store to outf (fp32) if *flag else outb (bf16), (M,N)
// Staging: global_load_lds (wave-uniform LDS base; HW adds lane*16B).
template <int EPI>
__global__ __launch_bounds__(256)
void gemm_bt(const bf16* __restrict__ A, const bf16* __restrict__ B,
             const bf16* __restrict__ bias,
             bf16* __restrict__ o0, bf16* __restrict__ o1,
             float* __restrict__ outf, bf16* __restrict__ outb,
             int K, int N, const int* __restrict__ flag) {
    __shared__ bf16 As[128 * 32];
    __shared__ bf16 Bs[128 * 32];
    const int tid = threadIdx.x;
    const int bm = blockIdx.x, bn = blockIdx.y;
    const bf16* Ab = A + (size_t)bm * 128 * K;
    const bf16* Bb = B + (size_t)bn * 128 * K;
    const int w = tid >> 6, lane = tid & 63, lm = lane & 15, lq = lane >> 4;
    const int m_off = (w >> 1) * 64, n_off = (w & 1) * 64;
    const int of32 = (EPI == 1) ? *flag : 0;
    f32x4 acc[4][4];
#pragma unroll
    for (int i = 0; i < 4; i++)
#pragma unroll
        for (int j = 0; j < 4; j++) { acc[i][j][0]=0.f; acc[i][j][1]=0.f; acc[i][j][2]=0.f; acc[i][j][3]=0.f; }

    const int r0 = tid * 8;            // per-lane element offset (16B per lane)
    const int row0 = r0 >> 5, col0 = r0 & 31;
    const int wb = w * 512;            // wave-uniform element base (w*1024B)
    for (int k0 = 0; k0 < K; k0 += 32) {
        __syncthreads();
        const bf16* gA0 = Ab + (size_t)row0 * K        + k0 + col0;
        const bf16* gA1 = Ab + (size_t)(row0 + 64) * K + k0 + col0;
        const bf16* gB0 = Bb + (size_t)row0 * K        + k0 + col0;
        const bf16* gB1 = Bb + (size_t)(row0 + 64) * K + k0 + col0;
#ifdef HAS_GLL
        __builtin_amdgcn_global_load_lds((const __attribute__((address_space(1))) void*)gA0,
                                         (__attribute__((address_space(3))) void*)&As[wb], 16, 0, 0);
        __builtin_amdgcn_global_load_lds((const __attribute__((address_space(1))) void*)gA1,
                                         (__attribute__((address_space(3))) void*)&As[wb + 2048], 16, 0, 0);
        __builtin_amdgcn_global_load_lds((const __attribute__((address_space(1))) void*)gB0,
                                         (__attribute__((address_space(3))) void*)&Bs[wb], 16, 0, 0);
        __builtin_amdgcn_global_load_lds((const __attribute__((address_space(1))) void*)gB1,
                                         (__attribute__((address_space(3))) void*)&Bs[wb + 2048], 16, 0, 0);
#else
        *(int4*)(&As[r0])        = *(const int4*)gA0;
        *(int4*)(&As[r0 + 2048]) = *(const int4*)gA1;
        *(int4*)(&Bs[r0])        = *(const int4*)gB0;
        *(int4*)(&Bs[r0 + 2048]) = *(const int4*)gB1;
#endif
        __syncthreads();
        bf16x8 af[4], bg[4];
#pragma unroll
        for (int i = 0; i < 4; i++) af[i] = *(const bf16x8*)&As[(m_off + i * 16 + lm) * 32 + lq * 8];
#pragma unroll
        for (int j = 0; j < 4; j++) bg[j] = *(const bf16x8*)&Bs[(n_off + j * 16 + lm) * 32 + lq * 8];
#pragma unroll
        for (int i = 0; i < 4; i++)
#pragma unroll
            for (int j = 0; j < 4; j++)
                acc[i][j] = __builtin_amdgcn_mfma_f32_16x16x32_bf16(af[i], bg[j], acc[i][j], 0, 0, 0);
    }
    const int gm0 = bm * 128 + m_off, gn0 = bn * 128 + n_off;
#pragma unroll
    for (int i = 0; i < 4; i++) {
#pragma unroll
        for (int j = 0; j < 4; j++) {
            const int gn = gn0 + j * 16 + lm;
            const float bv = (float)bias[gn];
#pragma unroll
            for (int e = 0; e < 4; e++) {
                const int gm = gm0 + i * 16 + lq * 4 + e;
                float v = acc[i][j][e] + bv;
                if (EPI == 0) {
                    v = gelu_fast(v);
                    if (gn < 2048) o0[(size_t)gm * 2048 + gn] = (bf16)v;
                    else           o1[(size_t)gm * 2048 + (gn - 2048)] = (bf16)v;
                } else {
                    if (of32) outf[(size_t)gm * N + gn] = v;
                    else      outb[(size_t)gm * N + gn] = (bf16)v;
                }
            }
        }
    }
}

// ---------------- LayerNorm(2048) + ReLU, in-place bf16 ---------------------
__global__ __launch_bounds__(256)
void ln_relu(bf16* __restrict__ z, const bf16* __restrict__ g, const bf16* __restrict__ b) {
    const int row = blockIdx.x;
    bf16* zr = z + (size_t)row * 2048;
    const int t = threadIdx.x;
    bf16x4 a0 = *(bf16x4*)(zr + t * 4);
    bf16x4 a1 = *(bf16x4*)(zr + 1024 + t * 4);
    float v0[4], v1[4];
#pragma unroll
    for (int i = 0; i < 4; i++) { v0[i] = (float)a0[i]; v1[i] = (float)a1[i]; }
    float s = 0.f, q = 0.f;
#pragma unroll
    for (int i = 0; i < 4; i++) { s += v0[i] + v1[i]; q += v0[i] * v0[i] + v1[i] * v1[i]; }
#pragma unroll
    for (int off = 32; off >= 1; off >>= 1) { s += __shfl_down(s, off); q += __shfl_down(q, off); }
    __shared__ float red[8];
    __shared__ float mv[2];
    const int wv = t >> 6;
    if ((t & 63) == 0) { red[wv] = s; red[4 + wv] = q; }
    __syncthreads();
    if (t == 0) {
        float S = red[0] + red[1] + red[2] + red[3];
        float Q = red[4] + red[5] + red[6] + red[7];
        float mu = S * (1.f / 2048.f);
        float var = Q * (1.f / 2048.f) - mu * mu;
        mv[0] = mu; mv[1] = rsqrtf(var + LNEPS);
    }
    __syncthreads();
    const float mu = mv[0], ri = mv[1];
#pragma unroll
    for (int i = 0; i < 4; i++) {
        int c0 = t * 4 + i, c1 = 1024 + t * 4 + i;
        a0[i] = (bf16)fmaxf((v0[i] - mu) * ri * (float)g[c0] + (float)b[c0], 0.f);
        a1[i] = (bf16)fmaxf((v1[i] - mu) * ri * (float)g[c1] + (float)b[c1], 0.f);
    }
    *(bf16x4*)(zr + t * 4) = a0;
    *(bf16x4*)(zr + 1024 + t * 4) = a1;
}

// ---------------- xmB [b][d=1024][n=2048] -> xmT [b][n][d] ------------------
__global__ __launch_bounds__(256)
void transpose_xm(const bf16* __restrict__ src, bf16* __restrict__ dst) {
    // grid: (32 ntile, 16 dtile, 8 b)
    const int n0 = blockIdx.x * 64, d0 = blockIdx.y * 64, b = blockIdx.z;
    const bf16* S = src + (size_t)b * 1024 * 2048;
    bf16* Dst = dst + (size_t)b * 2048 * 1024;
    __shared__ bf16 tl[64 * 72];
    const int t = threadIdx.x;
    const int tr = t >> 2, tc = (t & 3) * 16;
    bf16x8 v0 = *(const bf16x8*)(S + (size_t)(d0 + tr) * 2048 + n0 + tc);
    bf16x8 v1 = *(const bf16x8*)(S + (size_t)(d0 + tr) * 2048 + n0 + tc + 8);
    *(bf16x8*)&tl[tr * 72 + tc] = v0;
    *(bf16x8*)&tl[tr * 72 + tc + 8] = v1;
    __syncthreads();
    bf16 o[16];
#pragma unroll
    for (int i = 0; i < 16; i++) o[i] = tl[(tc + i) * 72 + tr];
    *(bf16x8*)(Dst + (size_t)(n0 + tr) * 1024 + d0 + tc) = *(bf16x8*)&o[0];
    *(bf16x8*)(Dst + (size_t)(n0 + tr) * 1024 + d0 + tc + 8) = *(bf16x8*)&o[8];
}

// ---- bases init: b0 bf16 [1024][64] -> fp32 state + bf16 hi/lo mirrors -----
__global__ __launch_bounds__(256)
void bases_init2(const bf16* __restrict__ b0, float* __restrict__ bases,
                 bf16* __restrict__ bNh, bf16* __restrict__ bNl,
                 bf16* __restrict__ bTh, bf16* __restrict__ bTl) {
    // grid (16 dtile, 8 b)
    const int d0 = blockIdx.x * 64, b = blockIdx.y;
    __shared__ bf16 tl[64 * 72];
    const int t = threadIdx.x;
    const int tr = t >> 2, tc = (t & 3) * 16;
    bf16x8 v0 = *(const bf16x8*)(b0 + (size_t)(d0 + tr) * 64 + tc);
    bf16x8 v1 = *(const bf16x8*)(b0 + (size_t)(d0 + tr) * 64 + tc + 8);
    *(bf16x8*)&tl[tr * 72 + tc] = v0;
    *(bf16x8*)&tl[tr * 72 + tc + 8] = v1;
    bf16x8 zz;
#pragma unroll
    for (int i = 0; i < 8; i++) zz[i] = (bf16)0.f;
    f32x4 f0, f1, f2, f3;
#pragma unroll
    for (int i = 0; i < 4; i++) { f0[i]=(float)v0[i]; f1[i]=(float)v0[i+4]; f2[i]=(float)v1[i]; f3[i]=(float)v1[i+4]; }
    const size_t nb = (size_t)b * 1024 * 64 + (size_t)(d0 + tr) * 64 + tc;
    *(f32x4*)(bases + nb)      = f0;
    *(f32x4*)(bases + nb + 4)  = f1;
    *(f32x4*)(bases + nb + 8)  = f2;
    *(f32x4*)(bases + nb + 12) = f3;
    *(bf16x8*)(bNh + nb)     = v0;
    *(bf16x8*)(bNh + nb + 8) = v1;
    *(bf16x8*)(bNl + nb)     = zz;
    *(bf16x8*)(bNl + nb + 8) = zz;
    __syncthreads();
    bf16 o[16];
#pragma unroll
    for (int i = 0; i < 16; i++) o[i] = tl[(tc + i) * 72 + tr];
    const size_t tb = (size_t)b * 64 * 1024 + (size_t)tr * 1024 + d0 + tc;
    *(bf16x8*)(bTh + tb)     = *(bf16x8*)&o[0];
    *(bf16x8*)(bTh + tb + 8) = *(bf16x8*)&o[8];
    *(bf16x8*)(bTl + tb)     = zz;
    *(bf16x8*)(bTl + tb + 8) = zz;
}

// ---- gram64p: partial gram over a K-slice. grid (NKS ksplit, 8 b) ----------
// Gp[b][ks][r][s] = sum_{k in slice} T[r][k]T[s][k]; 3-term hi/lo MFMA.
__global__ __launch_bounds__(256)
void gram64p(const bf16* __restrict__ Th, const bf16* __restrict__ Tl,
             int K, float* __restrict__ Gp) {
    const int ks = blockIdx.x, b = blockIdx.y;
    const int KC = K / NKS;
    const int kbeg = ks * KC, kend = kbeg + KC;
    const bf16* H = Th + (size_t)b * 64 * K;
    const bf16* L = Tl + (size_t)b * 64 * K;
    __shared__ bf16 Hs[64 * 40], Ls[64 * 40];
    const int t = threadIdx.x, lane = t & 63, w = t >> 6;
    const int lm = lane & 15, lq = lane >> 4;
    const int srow = t >> 2, scol = (t & 3) * 8;
    f32x4 acc[4];
#pragma unroll
    for (int j = 0; j < 4; j++) { acc[j][0]=0.f; acc[j][1]=0.f; acc[j][2]=0.f; acc[j][3]=0.f; }
    for (int k0 = kbeg; k0 < kend; k0 += 32) {
        __syncthreads();
        *(int4*)&Hs[srow * 40 + scol] = *(const int4*)(H + (size_t)srow * K + k0 + scol);
        *(int4*)&Ls[srow * 40 + scol] = *(const int4*)(L + (size_t)srow * K + k0 + scol);
        __syncthreads();
        bf16x8 aH = *(const bf16x8*)&Hs[(w * 16 + lm) * 40 + lq * 8];
        bf16x8 aL = *(const bf16x8*)&Ls[(w * 16 + lm) * 40 + lq * 8];
#pragma unroll
        for (int j = 0; j < 4; j++) {
            bf16x8 bH = *(const bf16x8*)&Hs[(j * 16 + lm) * 40 + lq * 8];
            bf16x8 bL = *(const bf16x8*)&Ls[(j * 16 + lm) * 40 + lq * 8];
            acc[j] = __builtin_amdgcn_mfma_f32_16x16x32_bf16(aH, bH, acc[j], 0, 0, 0);
            acc[j] = __builtin_amdgcn_mfma_f32_16x16x32_bf16(aH, bL, acc[j], 0, 0, 0);
            acc[j] = __builtin_amdgcn_mfma_f32_16x16x32_bf16(aL, bH, acc[j], 0, 0, 0);
        }
    }
    float* Gb = Gp + ((size_t)b * NKS + ks) * 4096;
#pragma unroll
    for (int j = 0; j < 4; j++)
#pragma unroll
        for (int e = 0; e < 4; e++)
            Gb[(w * 16 + lq * 4 + e) * 64 + j * 16 + lm] = acc[j][e];
}

// ---- coef step: num = xm^T @ bases via MFMA (A=xmT, W=basesT hi/lo) --------
// K-step 64 + reg-staged double-buffered LDS (issue-early / write-late).
// MODE 0: coef = softmax_r(num); MODE 1: coef *= num/(coef@btb+eps),
// btb = sum of NKS partials; writes fp32 + hi/lo mirrors.
// grid (32 ntiles of 64, 8 b); 256 thr; per-wave: 16 n rows x 64 r
template <int MODE>
__global__ __launch_bounds__(256)
void coef_step(const bf16* __restrict__ xmT, const bf16* __restrict__ bTh,
               const bf16* __restrict__ bTl, const float* __restrict__ btb,
               float* __restrict__ coef,
               bf16* __restrict__ cNh, bf16* __restrict__ cNl,
               bf16* __restrict__ cTh, bf16* __restrict__ cTl) {
    const int n0 = blockIdx.x * 64, b = blockIdx.y;
    const bf16* X = xmT + (size_t)b * 2048 * 1024 + (size_t)n0 * 1024;
    const bf16* H = bTh + (size_t)b * 64 * 1024;
    const bf16* L = bTl + (size_t)b * 64 * 1024;
    __shared__ bf16 xs[2][64 * 72], hs[2][64 * 72], ls[2][64 * 72];
    __shared__ float cold[(MODE == 1) ? 64 * 65 : 1];
    __shared__ float gsm[(MODE == 1) ? 64 * 64 : 1];
    const int t = threadIdx.x;
    float* Cb = coef + (size_t)b * 2048 * 64 + (size_t)n0 * 64;
    if constexpr (MODE == 1) {
        const int rr = t >> 2, cc = (t & 3) * 16;
#pragma unroll
        for (int i = 0; i < 4; i++)
            *(f32x4*)&cold[rr * 65 + cc + i * 4] = *(const f32x4*)(Cb + (size_t)rr * 64 + cc + i * 4);
        const float* Gb = btb + (size_t)b * NKS * 4096;
#pragma unroll
        for (int i = 0; i < 4; i++) {
            f32x4 s4; s4[0]=0.f; s4[1]=0.f; s4[2]=0.f; s4[3]=0.f;
#pragma unroll
            for (int ks = 0; ks < NKS; ks++)
                s4 += *(const f32x4*)(Gb + ks * 4096 + rr * 64 + cc + i * 4);
            *(f32x4*)&gsm[rr * 64 + cc + i * 4] = s4;
        }
    }
    const int lane = t & 63, w = t >> 6, lm = lane & 15, lq = lane >> 4;
    // staging: per thread 2 int4 per tensor; row srow, cols scol..scol+15
    const int srow = t >> 2, scol = (t & 3) * 16;
    int4 rx0, rx1, rh0, rh1, rl0, rl1;
    {   // prologue: stage kt=0 into buf 0
        rx0 = *(const int4*)(X + (size_t)srow * 1024 + scol);
        rx1 = *(const int4*)(X + (size_t)srow * 1024 + scol + 8);
        rh0 = *(const int4*)(H + (size_t)srow * 1024 + scol);
        rh1 = *(const int4*)(H + (size_t)srow * 1024 + scol + 8);
        rl0 = *(const int4*)(L + (size_t)srow * 1024 + scol);
        rl1 = *(const int4*)(L + (size_t)srow * 1024 + scol + 8);
        bf16* xb = &xs[0][srow * 72 + scol];
        bf16* hb = &hs[0][srow * 72 + scol];
        bf16* lb = &ls[0][srow * 72 + scol];
        *(int4*)xb = rx0; *(int4*)(xb + 8) = rx1;
        *(int4*)hb = rh0; *(int4*)(hb + 8) = rh1;
        *(int4*)lb = rl0; *(int4*)(lb + 8) = rl1;
    }
    __syncthreads();
    f32x4 acc[4];
#pragma unroll
    for (int j = 0; j < 4; j++) { acc[j][0]=0.f; acc[j][1]=0.f; acc[j][2]=0.f; acc[j][3]=0.f; }
    int cur = 0;
    for (int kt = 0; kt < 16; kt++) {
        if (kt < 15) {          // issue next-slab loads early (hide under MFMA)
            const int k0 = (kt + 1) * 64;
            rx0 = *(const int4*)(X + (size_t)srow * 1024 + k0 + scol);
            rx1 = *(const int4*)(X + (size_t)srow * 1024 + k0 + scol + 8);
            rh0 = *(const int4*)(H + (size_t)srow * 1024 + k0 + scol);
            rh1 = *(const int4*)(H + (size_t)srow * 1024 + k0 + scol + 8);
            rl0 = *(const int4*)(L + (size_t)srow * 1024 + k0 + scol);
            rl1 = *(const int4*)(L + (size_t)srow * 1024 + k0 + scol + 8);
        }
        {   // compute current slab (64 k): per-acc order kh0-h,kh0-l,kh1-h,kh1-l
            bf16x8 a0 = *(const bf16x8*)&xs[cur][(w * 16 + lm) * 72 + lq * 8];
            bf16x8 a1 = *(const bf16x8*)&xs[cur][(w * 16 + lm) * 72 + 32 + lq * 8];
#pragma unroll
            for (int j = 0; j < 4; j++) {
                bf16x8 bh0 = *(const bf16x8*)&hs[cur][(j * 16 + lm) * 72 + lq * 8];
                bf16x8 bl0 = *(const bf16x8*)&ls[cur][(j * 16 + lm) * 72 + lq * 8];
                acc[j] = __builtin_amdgcn_mfma_f32_16x16x32_bf16(a0, bh0, acc[j], 0, 0, 0);
                acc[j] = __builtin_amdgcn_mfma_f32_16x16x32_bf16(a0, bl0, acc[j], 0, 0, 0);
                bf16x8 bh1 = *(const bf16x8*)&hs[cur][(j * 16 + lm) * 72 + 32 + lq * 8];
                bf16x8 bl1 = *(const bf16x8*)&ls[cur][(j * 16 + lm) * 72 + 32 + lq * 8];
                acc[j] = __builtin_amdgcn_mfma_f32_16x16x32_bf16(a1, bh1, acc[j], 0, 0, 0);
                acc[j] = __builtin_amdgcn_mfma_f32_16x16x32_bf16(a1, bl1, acc[j], 0, 0, 0);
            }
        }
        if (kt < 15) {          // write next slab to alternate buffer
            bf16* xb = &xs[cur ^ 1][srow * 72 + scol];
            bf16* hb = &hs[cur ^ 1][srow * 72 + scol];
            bf16* lb = &ls[cur ^ 1][srow * 72 + scol];
            *(int4*)xb = rx0; *(int4*)(xb + 8) = rx1;
            *(int4*)hb = rh0; *(int4*)(hb + 8) = rh1;
            *(int4*)lb = rl0; *(int4*)(lb + 8) = rl1;
        }
        __syncthreads();
        cur ^= 1;
    }
    // num value acc[j][e] lives at n-local = w*16+lq*4+e, r = j*16+lm
    const int nbase = w * 16 + lq * 4;
    float out[4][4];
    if constexpr (MODE == 0) {
#pragma unroll
        for (int e = 0; e < 4; e++) {
            float m = fmaxf(fmaxf(acc[0][e], acc[1][e]), fmaxf(acc[2][e], acc[3][e]));
#pragma unroll
            for (int off = 1; off < 16; off <<= 1) m = fmaxf(m, __shfl_xor(m, off));
            float ex[4], s = 0.f;
#pragma unroll
            for (int j = 0; j < 4; j++) { ex[j] = expf(acc[j][e] - m); s += ex[j]; }
#pragma unroll
            for (int off = 1; off < 16; off <<= 1) s += __shfl_xor(s, off);
            const float inv = 1.f / s;
#pragma unroll
            for (int j = 0; j < 4; j++) out[j][e] = ex[j] * inv;
        }
    } else {
        float den[4][4];
#pragma unroll
        for (int j = 0; j < 4; j++)
#pragma unroll
            for (int e = 0; e < 4; e++) den[j][e] = 0.f;
#pragma unroll 8
        for (int s = 0; s < 64; s++) {
            float g4[4], c4[4];
#pragma unroll
            for (int j = 0; j < 4; j++) g4[j] = gsm[s * 64 + j * 16 + lm];
#pragma unroll
            for (int e = 0; e < 4; e++) c4[e] = cold[(nbase + e) * 65 + s];
#pragma unroll
            for (int j = 0; j < 4; j++)
#pragma unroll
                for (int e = 0; e < 4; e++) den[j][e] += c4[e] * g4[j];
        }
#pragma unroll
        for (int j = 0; j < 4; j++)
#pragma unroll
            for (int e = 0; e < 4; e++)
                out[j][e] = cold[(nbase + e) * 65 + j * 16 + lm] * acc[j][e] / (den[j][e] + NMF_EPS);
    }
    // fp32 canonical (+ N mirrors in MODE 1)
#pragma unroll
    for (int j = 0; j < 4; j++) {
        const int r = j * 16 + lm;
#pragma unroll
        for (int e = 0; e < 4; e++) {
            const int nl = nbase + e;
            Cb[(size_t)nl * 64 + r] = out[j][e];
            if constexpr (MODE == 1) {
                bf16 h, l2;
                split2(out[j][e], h, l2);
                cNh[(size_t)b * 2048 * 64 + (size_t)(n0 + nl) * 64 + r] = h;
                cNl[(size_t)b * 2048 * 64 + (size_t)(n0 + nl) * 64 + r] = l2;
            }
        }
    }
    if constexpr (MODE == 1) {
        // T mirrors via LDS transpose (reuse cold as [r][65] tile)
        __syncthreads();
#pragma unroll
        for (int j = 0; j < 4; j++)
#pragma unroll
            for (int e = 0; e < 4; e++)
                cold[(j * 16 + lm) * 65 + nbase + e] = out[j][e];
        __syncthreads();
        const int rr = t >> 2, nc = (t & 3) * 16;
        bf16 hh[16], ll2[16];
#pragma unroll
        for (int i = 0; i < 16; i++) split2(cold[rr * 65 + nc + i], hh[i], ll2[i]);
        const size_t tb = (size_t)b * 64 * 2048 + (size_t)rr * 2048 + n0 + nc;
        *(bf16x8*)(cTh + tb)     = *(bf16x8*)&hh[0];
        *(bf16x8*)(cTh + tb + 8) = *(bf16x8*)&hh[8];
        *(bf16x8*)(cTl + tb)     = *(bf16x8*)&ll2[0];
        *(bf16x8*)(cTl + tb + 8) = *(bf16x8*)&ll2[8];
    }
}

// ---- bases step: numT = coefT @ xm^T via MFMA (A=coefT hi/lo, W=xm) --------
// K-step 64 + reg-staged double-buffered LDS. ctc = sum of NKS partials.
// bases[d][r] *= num[d][r] / (bases@ctc + eps); grid (32 dtiles of 32, 8 b)
__global__ __launch_bounds__(256)
void bases_step(const bf16* __restrict__ xm, const bf16* __restrict__ cTh,
                const bf16* __restrict__ cTl, const float* __restrict__ ctc,
                float* __restrict__ bases,
                bf16* __restrict__ bNh, bf16* __restrict__ bNl,
                bf16* __restrict__ bTh, bf16* __restrict__ bTl) {
    const int d0 = blockIdx.x * 32, b = blockIdx.y;
    const bf16* X = xm + (size_t)b * 1024 * 2048 + (size_t)d0 * 2048;
    const bf16* H = cTh + (size_t)b * 64 * 2048;
    const bf16* L = cTl + (size_t)b * 64 * 2048;
    __shared__ bf16 hs[2][64 * 72], ls[2][64 * 72], xds[2][32 * 72];
    __shared__ float bold[32 * 65];
    __shared__ float gsm[64 * 64];
    const int t = threadIdx.x;
    float* Bb = bases + (size_t)b * 1024 * 64 + (size_t)d0 * 64;
    {
        const int rr = t >> 3, cc = (t & 7) * 8;
        *(f32x4*)&bold[rr * 65 + cc]     = *(const f32x4*)(Bb + (size_t)rr * 64 + cc);
        *(f32x4*)&bold[rr * 65 + cc + 4] = *(const f32x4*)(Bb + (size_t)rr * 64 + cc + 4);
        const int r2 = t >> 2, c2 = (t & 3) * 16;
        const float* Gb = ctc + (size_t)b * NKS * 4096;
#pragma unroll
        for (int i = 0; i < 4; i++) {
            f32x4 s4; s4[0]=0.f; s4[1]=0.f; s4[2]=0.f; s4[3]=0.f;
#pragma unroll
            for (int ks = 0; ks < NKS; ks++)
                s4 += *(const f32x4*)(Gb + ks * 4096 + r2 * 64 + c2 + i * 4);
            *(f32x4*)&gsm[r2 * 64 + c2 + i * 4] = s4;
        }
    }
    const int lane = t & 63, w = t >> 6, lm = lane & 15, lq = lane >> 4;
    const int srow = t >> 2, scol = (t & 3) * 16;   // hs/ls: 64 rows x 64 cols
    const int xrow = t >> 3, xcol = (t & 7) * 8;    // xds:   32 rows x 64 cols
    int4 rh0, rh1, rl0, rl1, rxd;
    {   // prologue: stage kt=0 into buf 0
        rh0 = *(const int4*)(H + (size_t)srow * 2048 + scol);
        rh1 = *(const int4*)(H + (size_t)srow * 2048 + scol + 8);
        rl0 = *(const int4*)(L + (size_t)srow * 2048 + scol);
        rl1 = *(const int4*)(L + (size_t)srow * 2048 + scol + 8);
        rxd = *(const int4*)(X + (size_t)xrow * 2048 + xcol);
        bf16* hb = &hs[0][srow * 72 + scol];
        bf16* lb = &ls[0][srow * 72 + scol];
        *(int4*)hb = rh0; *(int4*)(hb + 8) = rh1;
        *(int4*)lb = rl0; *(int4*)(lb + 8) = rl1;
        *(int4*)&xds[0][xrow * 72 + xcol] = rxd;
    }
    __syncthreads();
    f32x4 acc[2];
#pragma unroll
    for (int j = 0; j < 2; j++) { acc[j][0]=0.f; acc[j][1]=0.f; acc[j][2]=0.f; acc[j][3]=0.f; }
    int cur = 0;
    for (int kt = 0; kt < 32; kt++) {
        if (kt < 31) {
            const int k0 = (kt + 1) * 64;
            rh0 = *(const int4*)(H + (size_t)srow * 2048 + k0 + scol);
            rh1 = *(const int4*)(H + (size_t)srow * 2048 + k0 + scol + 8);
            rl0 = *(const int4*)(L + (size_t)srow * 2048 + k0 + scol);
            rl1 = *(const int4*)(L + (size_t)srow * 2048 + k0 + scol + 8);
            rxd = *(const int4*)(X + (size_t)xrow * 2048 + k0 + xcol);
        }
        {
            bf16x8 ah0 = *(const bf16x8*)&hs[cur][(w * 16 + lm) * 72 + lq * 8];
            bf16x8 al0 = *(const bf16x8*)&ls[cur][(w * 16 + lm) * 72 + lq * 8];
            bf16x8 ah1 = *(const bf16x8*)&hs[cur][(w * 16 + lm) * 72 + 32 + lq * 8];
            bf16x8 al1 = *(const bf16x8*)&ls[cur][(w * 16 + lm) * 72 + 32 + lq * 8];
#pragma unroll
            for (int j = 0; j < 2; j++) {
                bf16x8 bx0 = *(const bf16x8*)&xds[cur][(j * 16 + lm) * 72 + lq * 8];
                acc[j] = __builtin_amdgcn_mfma_f32_16x16x32_bf16(ah0, bx0, acc[j], 0, 0, 0);
                acc[j] = __builtin_amdgcn_mfma_f32_16x16x32_bf16(al0, bx0, acc[j], 0, 0, 0);
                bf16x8 bx1 = *(const bf16x8*)&xds[cur][(j * 16 + lm) * 72 + 32 + lq * 8];
                acc[j] = __builtin_amdgcn_mfma_f32_16x16x32_bf16(ah1, bx1, acc[j], 0, 0, 0);
                acc[j] = __builtin_amdgcn_mfma_f32_16x16x32_bf16(al1, bx1, acc[j], 0, 0, 0);
            }
        }
        if (kt < 31) {
            bf16* hb = &hs[cur ^ 1][srow * 72 + scol];
            bf16* lb = &ls[cur ^ 1][srow * 72 + scol];
            *(int4*)hb = rh0; *(int4*)(hb + 8) = rh1;
            *(int4*)lb = rl0; *(int4*)(lb + 8) = rl1;
            *(int4*)&xds[cur ^ 1][xrow * 72 + xcol] = rxd;
        }
        __syncthreads();
        cur ^= 1;
    }
    // numT value acc[j][e] at r = w*16+lq*4+e, d-local = j*16+lm
    const int rbase = w * 16 + lq * 4;
    float den[2][4];
#pragma unroll
    for (int j = 0; j < 2; j++)
#pragma unroll
        for (int e = 0; e < 4; e++) den[j][e] = 0.f;
#pragma unroll 8
    for (int s = 0; s < 64; s++) {
        float g4[4], b2[2];
#pragma unroll
        for (int e = 0; e < 4; e++) g4[e] = gsm[s * 64 + rbase + e];
#pragma unroll
        for (int j = 0; j < 2; j++) b2[j] = bold[(j * 16 + lm) * 65 + s];
#pragma unroll
        for (int j = 0; j < 2; j++)
#pragma unroll
            for (int e = 0; e < 4; e++) den[j][e] += b2[j] * g4[e];
    }
    float out[2][4];
#pragma unroll
    for (int j = 0; j < 2; j++)
#pragma unroll
        for (int e = 0; e < 4; e++)
            out[j][e] = bold[(j * 16 + lm) * 65 + rbase + e] * acc[j][e] / (den[j][e] + NMF_EPS);
    __syncthreads();
#pragma unroll
    for (int j = 0; j < 2; j++)
#pragma unroll
        for (int e = 0; e < 4; e++)
            bold[(j * 16 + lm) * 65 + rbase + e] = out[j][e];
    __syncthreads();
    {   // fp32 + N mirrors
        const int dd = t >> 3, rc = (t & 7) * 8;
        float v[8];
#pragma unroll
        for (int i = 0; i < 8; i++) v[i] = bold[dd * 65 + rc + i];
        *(f32x4*)(Bb + (size_t)dd * 64 + rc)     = *(f32x4*)&v[0];
        *(f32x4*)(Bb + (size_t)dd * 64 + rc + 4) = *(f32x4*)&v[4];
        bf16 hv[8], lv[8];
#pragma unroll
        for (int i = 0; i < 8; i++) split2(v[i], hv[i], lv[i]);
        const size_t nb = (size_t)b * 1024 * 64 + (size_t)(d0 + dd) * 64 + rc;
        *(bf16x8*)(bNh + nb) = *(bf16x8*)&hv[0];
        *(bf16x8*)(bNl + nb) = *(bf16x8*)&lv[0];
    }
    {   // T mirrors
        const int rr = t >> 2, dc = (t & 3) * 8;
        bf16 hv[8], lv[8];
#pragma unroll
        for (int i = 0; i < 8; i++) split2(bold[(dc + i) * 65 + rr], hv[i], lv[i]);
        const size_t tb = (size_t)b * 64 * 1024 + (size_t)rr * 1024 + d0 + dc;
        *(bf16x8*)(bTh + tb) = *(bf16x8*)&hv[0];
        *(bf16x8*)(bTl + tb) = *(bf16x8*)&lv[0];
    }
}

// ---- recon+gate: z1A[s][n] *= sum_r bases[s][r]*coef[n][r] via MFMA (K=64) -
// grid (16 ntiles of 128, 8 stiles of 128, 8 b)
__global__ __launch_bounds__(256)
void recon_gate2(bf16* __restrict__ z1A, const bf16* __restrict__ bNh,
                 const bf16* __restrict__ bNl, const bf16* __restrict__ cNh,
                 const bf16* __restrict__ cNl) {
    const int n0 = blockIdx.x * 128, s0 = blockIdx.y * 128, b = blockIdx.z;
    const bf16* Ah = bNh + (size_t)b * 1024 * 64 + (size_t)s0 * 64;
    const bf16* Al = bNl + (size_t)b * 1024 * 64 + (size_t)s0 * 64;
    const bf16* Bh = cNh + (size_t)b * 2048 * 64 + (size_t)n0 * 64;
    const bf16* Bl = cNl + (size_t)b * 2048 * 64 + (size_t)n0 * 64;
    __shared__ bf16 ahs[128 * 72], als[128 * 72], bhs[128 * 72], bls[128 * 72];
    const int t = threadIdx.x;
#pragma unroll
    for (int i = 0; i < 4; i++) {
        const int idx = t * 4 + i;            // 0..1023 chunks of 8
        const int r_ = idx >> 3, c_ = (idx & 7) * 8;
        *(int4*)&ahs[r_ * 72 + c_] = *(const int4*)(Ah + (size_t)r_ * 64 + c_);
        *(int4*)&als[r_ * 72 + c_] = *(const int4*)(Al + (size_t)r_ * 64 + c_);
        *(int4*)&bhs[r_ * 72 + c_] = *(const int4*)(Bh + (size_t)r_ * 64 + c_);
        *(int4*)&bls[r_ * 72 + c_] = *(const int4*)(Bl + (size_t)r_ * 64 + c_);
    }
    __syncthreads();
    const int lane = t & 63, w = t >> 6, lm = lane & 15, lq = lane >> 4;
    const int m_off = (w >> 1) * 64, n_off = (w & 1) * 64;
    f32x4 acc[4][4];
#pragma unroll
    for (int i = 0; i < 4; i++)
#pragma unroll
        for (int j = 0; j < 4; j++) { acc[i][j][0]=0.f; acc[i][j][1]=0.f; acc[i][j][2]=0.f; acc[i][j][3]=0.f; }
#pragma unroll
    for (int kk = 0; kk < 2; kk++) {
        bf16x8 afh[4], afl[4], bgh[4], bgl[4];
#pragma unroll
        for (int i = 0; i < 4; i++) {
            afh[i] = *(const bf16x8*)&ahs[(m_off + i * 16 + lm) * 72 + kk * 32 + lq * 8];
            afl[i] = *(const bf16x8*)&als[(m_off + i * 16 + lm) * 72 + kk * 32 + lq * 8];
        }
#pragma unroll
        for (int j = 0; j < 4; j++) {
            bgh[j] = *(const bf16x8*)&bhs[(n_off + j * 16 + lm) * 72 + kk * 32 + lq * 8];
            bgl[j] = *(const bf16x8*)&bls[(n_off + j * 16 + lm) * 72 + kk * 32 + lq * 8];
        }
#pragma unroll
        for (int i = 0; i < 4; i++)
#pragma unroll
            for (int j = 0; j < 4; j++) {
                acc[i][j] = __builtin_amdgcn_mfma_f32_16x16x32_bf16(afh[i], bgh[j], acc[i][j], 0, 0, 0);
                acc[i][j] = __builtin_amdgcn_mfma_f32_16x16x32_bf16(afh[i], bgl[j], acc[i][j], 0, 0, 0);
                acc[i][j] = __builtin_amdgcn_mfma_f32_16x16x32_bf16(afl[i], bgh[j], acc[i][j], 0, 0, 0);
            }
    }
    bf16* Z = z1A + ((size_t)b * 1024 + s0) * 2048 + n0;
#pragma unroll
    for (int i = 0; i < 4; i++)
#pragma unroll
        for (int j = 0; j < 4; j++) {
            const int gn = n_off + j * 16 + lm;
#pragma unroll
            for (int e = 0; e < 4; e++) {
                const int gm = m_off + i * 16 + lq * 4 + e;
                bf16* p = Z + (size_t)gm * 2048 + gn;
                *p = (bf16)((float)*p * acc[i][j][e]);
            }
        }
}

// ---------------------------------------------------------------------------
extern "C" void kernel_launch(void* const* d_in, const int* in_sizes, int n_in,
                              void* d_out, int out_size, void* d_ws, size_t ws_size,
                              hipStream_t stream) {
    (void)in_sizes; (void)n_in; (void)out_size; (void)ws_size;
    char* ws = (char*)d_ws;
    bf16*  z1A   = (bf16*)(ws);                   // 33554432 B (z1 -> gated A)
    bf16*  xmB   = (bf16*)(ws + 33554432);        // 33554432 B (z2 -> xm, [b][d][n])
    bf16*  xmT   = (bf16*)(ws + 67108864);        // 33554432 B (xm^T, [b][n][d])
    char*  ar    = ws + 100663296;                // bf16 input arena (~29.5 MB)
    bf16* xc   = (bf16*)(ar);                     // 8388608 el
    bf16* Uwc  = (bf16*)(ar + 16777216);          // 4194304
    bf16* Ubc  = (bf16*)(ar + 25165824);          // 4096
    bf16* lngc = (bf16*)(ar + 25174016);          // 2048
    bf16* lnbc = (bf16*)(ar + 25178112);          // 2048
    bf16* b0c  = (bf16*)(ar + 25182208);          // 65536
    bf16* Vwc  = (bf16*)(ar + 25313280);          // 2097152
    bf16* Vbc  = (bf16*)(ar + 29507584);          // 1024
    int*  dflag = (int*)(ar + 29509632);
    // NMF state overlays the arena prefix (xc/Uwc), which is dead after gemm0:
    float* bases = (float*)(ar);                  // 2097152
    float* coef  = (float*)(ar + 2097152);        // 4194304
    bf16* bTh = (bf16*)(ar + 6291456);            // 1048576 each
    bf16* bTl = (bf16*)(ar + 7340032);
    bf16* bNh = (bf16*)(ar + 8388608);
    bf16* bNl = (bf16*)(ar + 9437184);
    bf16* cTh = (bf16*)(ar + 10485760);           // 2097152 each
    bf16* cTl = (bf16*)(ar + 12582912);
    bf16* cNh = (bf16*)(ar + 14680064);
    bf16* cNl = (bf16*)(ar + 16777216);           // ends ar+18874368
    // Partial grams live in dead Uwc tail (free after gemm0):
    float* btb = (float*)(ar + 18874368);         // NKS=8 partials: 1048576 B
    float* ctc = (float*)(ar + 19922944);         // NKS=8 partials: 1048576 B
    // ends ar+20971520 < Ubc @ ar+25165824. Peak ws usage ~130.2 MB (= r4).

    detect_dtype<<<1, 256, 0, stream>>>(d_in[0], dflag);
    conv_all<<<dim3(2048), 256, 0, stream>>>(d_in[0], d_in[1], d_in[2], d_in[3],
                                             d_in[4], d_in[5], d_in[6], d_in[7],
                                             (bf16*)ar, dflag);

    // 1) h = gelu(x @ U_w^T + U_b) -> z1 (bf16) | z2 (bf16, xmB)
    gemm_bt<0><<<dim3(64, 32), 256, 0, stream>>>(xc, Uwc, Ubc, z1A, xmB,
                                                 nullptr, nullptr, 1024, 4096, nullptr);
    // 2) xm = relu(LN(z2)) in place; then materialize xm^T
    ln_relu<<<dim3(8192), 256, 0, stream>>>(xmB, lngc, lnbc);
    transpose_xm<<<dim3(32, 16, 8), 256, 0, stream>>>(xmB, xmT);
    // 3) NMF (fp32 state + bf16 hi/lo mirrors; all matmuls on MFMA)
    bases_init2<<<dim3(16, 8), 256, 0, stream>>>(b0c, bases, bNh, bNl, bTh, bTl);
    coef_step<0><<<dim3(32, 8), 256, 0, stream>>>(xmT, bTh, bTl, nullptr, coef,
                                                  nullptr, nullptr, nullptr, nullptr);
    for (int it = 0; it < 7; ++it) {
        gram64p<<<dim3(NKS, 8), 256, 0, stream>>>(bTh, bTl, 1024, btb);
        coef_step<1><<<dim3(32, 8), 256, 0, stream>>>(xmT, bTh, bTl, btb, coef,
                                                      cNh, cNl, cTh, cTl);
        if (it < 6) {
            gram64p<<<dim3(NKS, 8), 256, 0, stream>>>(cTh, cTl, 2048, ctc);
            bases_step<<<dim3(32, 8), 256, 0, stream>>>(xmB, cTh, cTl, ctc, bases,
                                                        bNh, bNl, bTh, bTl);
        }
    }
    // 4) A = z1 * (bases @ coef^T), in place over z1A (MFMA, K=64, 3-term)
    recon_gate2<<<dim3(16, 8, 8), 256, 0, stream>>>(z1A, bNh, bNl, cNh, cNl);
    // 5) out = A @ V_w^T + V_b   (fp32 out if inputs were fp32, else bf16)
    gemm_bt<1><<<dim3(64, 8), 256, 0, stream>>>(z1A, Vwc, Vbc, nullptr, nullptr,
                                                (float*)d_out, (bf16*)d_out,
                                                2048, 1024, dflag);
}